// Round 9
// baseline (504.829 us; speedup 1.0000x reference)
//
#include <hip/hip_runtime.h>
#include <stddef.h>

// Problem constants (from reference)
#define N_NODES 100000
#define N_EDGES 1600000
#define DIM_IN  48
#define DIM_U   128
#define DIM_OUT 128

#define SCAN_BLK 256
#define SCAN_NB  ((N_NODES + SCAN_BLK - 1) / SCAN_BLK)   // 391

// Established: f32 inputs, int32 indices, f32 out; checker vs bf16-rounded ref.
// R8: 483 us. Top dispatch fill_kernel 127 us, WRITE_SIZE 153 MB (line-granular
// writeback amplification: 2 scattered 4B stores/edge -> 2 lines/edge).
// R9: pack (src,w) into ONE int2 8B store/edge; fold df into prop pass 2.

// ---------------- zero-fill ----------------
__global__ __launch_bounds__(256) void zero_kernel(int* __restrict__ p, int n) {
    int i = blockIdx.x * 256 + threadIdx.x;
    if (i < n) p[i] = 0;
}

// ---------------- CSR build ----------------
__global__ __launch_bounds__(256) void count_kernel(const int* __restrict__ en,
                                                    int* __restrict__ cnt, int E) {
    int i = blockIdx.x * 256 + threadIdx.x;
    if (i < E) atomicAdd(&cnt[en[i]], 1);
}

// Stage 1: per-block sums of cnt chunks
__global__ __launch_bounds__(SCAN_BLK) void block_sum_kernel(const int* __restrict__ cnt,
                                                             int* __restrict__ bsum,
                                                             int n) {
    __shared__ int sdata[SCAN_BLK];
    int t = threadIdx.x;
    int i = blockIdx.x * SCAN_BLK + t;
    sdata[t] = (i < n) ? cnt[i] : 0;
    __syncthreads();
    for (int s = SCAN_BLK / 2; s > 0; s >>= 1) {
        if (t < s) sdata[t] += sdata[t + s];
        __syncthreads();
    }
    if (t == 0) bsum[blockIdx.x] = sdata[0];
}

// Stage 2: single-block exclusive scan of the block sums (512-wide)
__global__ __launch_bounds__(512) void scan_bsum_kernel(int* __restrict__ bsum, int nb) {
    __shared__ int part[512];
    int t = threadIdx.x;
    int v = (t < nb) ? bsum[t] : 0;
    part[t] = v;
    __syncthreads();
    for (int off = 1; off < 512; off <<= 1) {
        int u = (t >= off) ? part[t - off] : 0;
        __syncthreads();
        part[t] += u;
        __syncthreads();
    }
    if (t < nb) bsum[t] = part[t] - v;  // exclusive
}

// Stage 3: per-block local scan + global offset -> rowptr, cursor.
// ALIAS-SAFE vs cursor==cnt: each index read before written, same thread.
__global__ __launch_bounds__(SCAN_BLK) void scan_write_kernel(const int* __restrict__ cnt,
                                                              const int* __restrict__ bsum,
                                                              int* __restrict__ rowptr,
                                                              int* __restrict__ cursor,
                                                              int n, int E) {
    __shared__ int part[SCAN_BLK];
    int t = threadIdx.x;
    int i = blockIdx.x * SCAN_BLK + t;
    int v = (i < n) ? cnt[i] : 0;
    part[t] = v;
    __syncthreads();
    for (int off = 1; off < SCAN_BLK; off <<= 1) {
        int u = (t >= off) ? part[t - off] : 0;
        __syncthreads();
        part[t] += u;
        __syncthreads();
    }
    if (i < n) {
        int ex = bsum[blockIdx.x] + part[t] - v;
        rowptr[i] = ex;
        cursor[i] = ex;
    }
    if (blockIdx.x == 0 && t == 0) rowptr[n] = E;
}

// Scatter edge into CSR slot: ONE packed 8B store per edge (src, w-bits).
__global__ __launch_bounds__(256) void fill_kernel(const int* __restrict__ sn,
                                                   const int* __restrict__ en,
                                                   const float* __restrict__ dfs,
                                                   int* __restrict__ cursor,
                                                   int2* __restrict__ edges, int E) {
    int i = blockIdx.x * 256 + threadIdx.x;
    if (i >= E) return;
    int d = en[i];
    int pos = atomicAdd(&cursor[d], 1);
    int2 ed;
    ed.x = sn[i];
    ed.y = __float_as_int(dfs[i]);
    edges[pos] = ed;
}

// ---------------- propagation: per-node gather ----------------
// use_df=1 (pass 2): weight *= df[src], folded inline (df is 400KB, L2-hot).
__global__ __launch_bounds__(192) void prop_kernel(const float* __restrict__ yin,
                                                   float* __restrict__ yout,
                                                   const int* __restrict__ rowptr,
                                                   const int2* __restrict__ edges,
                                                   const float* __restrict__ df,
                                                   int use_df, int n_nodes) {
    int n = blockIdx.x * 4 + threadIdx.y;
    if (n >= n_nodes) return;
    int d = threadIdx.x;  // 0..47
    int lo = rowptr[n];
    int hi = rowptr[n + 1];
    float acc = 0.f;
    int e = lo;
    for (; e + 4 <= hi; e += 4) {
        int2 e0 = edges[e], e1 = edges[e + 1], e2 = edges[e + 2], e3 = edges[e + 3];
        float w0 = __int_as_float(e0.y);
        float w1 = __int_as_float(e1.y);
        float w2 = __int_as_float(e2.y);
        float w3 = __int_as_float(e3.y);
        if (use_df) {
            w0 *= df[e0.x]; w1 *= df[e1.x]; w2 *= df[e2.x]; w3 *= df[e3.x];
        }
        float v0 = yin[(size_t)e0.x * DIM_IN + d];
        float v1 = yin[(size_t)e1.x * DIM_IN + d];
        float v2 = yin[(size_t)e2.x * DIM_IN + d];
        float v3 = yin[(size_t)e3.x * DIM_IN + d];
        acc = fmaf(v0, w0, acc);
        acc = fmaf(v1, w1, acc);
        acc = fmaf(v2, w2, acc);
        acc = fmaf(v3, w3, acc);
    }
    for (; e < hi; ++e) {
        int2 ed = edges[e];
        float w = __int_as_float(ed.y);
        if (use_df) w *= df[ed.x];
        acc = fmaf(yin[(size_t)ed.x * DIM_IN + d], w, acc);
    }
    yout[(size_t)n * DIM_IN + d] = acc;
}

// ---------------- fallback: atomic scatter (R6 proven path) ----------------
__global__ __launch_bounds__(192) void scatter1_kernel(
    const float* __restrict__ yin, float* __restrict__ yout,
    const int* __restrict__ sn, const int* __restrict__ en,
    const float* __restrict__ dfs, int E)
{
    int e = blockIdx.x * 4 + threadIdx.y;
    if (e >= E) return;
    int d = threadIdx.x;
    int s = sn[e], dn = en[e];
    float v = yin[(size_t)s * DIM_IN + d] * dfs[e];
    atomicAdd(&yout[(size_t)dn * DIM_IN + d], v);
}
__global__ __launch_bounds__(192) void scatter2_kernel(
    const float* __restrict__ yin, float* __restrict__ yout,
    const int* __restrict__ sn, const int* __restrict__ en,
    const float* __restrict__ dfs, const float* __restrict__ df, int E)
{
    int e = blockIdx.x * 4 + threadIdx.y;
    if (e >= E) return;
    int d = threadIdx.x;
    int s = sn[e], dn = en[e];
    float w = dfs[e] * df[s];
    float v = yin[(size_t)s * DIM_IN + d] * w;
    atomicAdd(&yout[(size_t)dn * DIM_IN + d], v);
}
__global__ __launch_bounds__(256) void zerof_kernel(float* __restrict__ p, int n) {
    int i = blockIdx.x * 256 + threadIdx.x;
    if (i < n) p[i] = 0.0f;
}

// ---------------- tiled MLP: 64 nodes/block, 8x4 regs/thread ----------------
__global__ __launch_bounds__(256) void mlp_kernel(const float* __restrict__ y2,
                                                  const float* __restrict__ df,
                                                  const float* __restrict__ W1,
                                                  const float* __restrict__ b1,
                                                  const float* __restrict__ W2,
                                                  const float* __restrict__ b2,
                                                  float* __restrict__ out,
                                                  int n_nodes) {
    __shared__ float xs[64 * DIM_IN];  // 12.3 KB
    __shared__ float hs[64 * DIM_U];   // 32.8 KB
    int node0 = blockIdx.x * 64;
    int t = threadIdx.x;

    for (int i = t; i < 64 * DIM_IN; i += 256) {
        int n = node0 + i / DIM_IN;
        float v = 0.f;
        if (n < n_nodes) v = y2[(size_t)node0 * DIM_IN + i] * df[n];
        xs[i] = v;
    }
    __syncthreads();

    int cg = t & 31;   // cols 4*cg..4*cg+3
    int ng = t >> 5;   // nodes 8*ng..8*ng+7

    float acc[8][4];
    #pragma unroll
    for (int m = 0; m < 8; ++m)
        #pragma unroll
        for (int c = 0; c < 4; ++c) acc[m][c] = 0.f;
    const float* xbase = &xs[ng * 8 * DIM_IN];
    for (int k = 0; k < DIM_IN; ++k) {
        float4 wv = *(const float4*)&W1[k * DIM_U + cg * 4];
        #pragma unroll
        for (int m = 0; m < 8; ++m) {
            float xv = xbase[m * DIM_IN + k];
            acc[m][0] = fmaf(xv, wv.x, acc[m][0]);
            acc[m][1] = fmaf(xv, wv.y, acc[m][1]);
            acc[m][2] = fmaf(xv, wv.z, acc[m][2]);
            acc[m][3] = fmaf(xv, wv.w, acc[m][3]);
        }
    }
    {
        float4 bb = *(const float4*)&b1[cg * 4];
        #pragma unroll
        for (int m = 0; m < 8; ++m) {
            float4 h;
            h.x = fmaxf(acc[m][0] + bb.x, 0.f);
            h.y = fmaxf(acc[m][1] + bb.y, 0.f);
            h.z = fmaxf(acc[m][2] + bb.z, 0.f);
            h.w = fmaxf(acc[m][3] + bb.w, 0.f);
            *(float4*)&hs[(ng * 8 + m) * DIM_U + cg * 4] = h;
        }
    }
    __syncthreads();

    float acc2[8][4];
    #pragma unroll
    for (int m = 0; m < 8; ++m)
        #pragma unroll
        for (int c = 0; c < 4; ++c) acc2[m][c] = 0.f;
    const float* hbase = &hs[ng * 8 * DIM_U];
    for (int k = 0; k < DIM_U; ++k) {
        float4 wv = *(const float4*)&W2[k * DIM_OUT + cg * 4];
        #pragma unroll
        for (int m = 0; m < 8; ++m) {
            float hv = hbase[m * DIM_U + k];
            acc2[m][0] = fmaf(hv, wv.x, acc2[m][0]);
            acc2[m][1] = fmaf(hv, wv.y, acc2[m][1]);
            acc2[m][2] = fmaf(hv, wv.z, acc2[m][2]);
            acc2[m][3] = fmaf(hv, wv.w, acc2[m][3]);
        }
    }
    {
        float4 bb = *(const float4*)&b2[cg * 4];
        #pragma unroll
        for (int m = 0; m < 8; ++m) {
            int n = node0 + ng * 8 + m;
            if (n < n_nodes) {
                float4 o;
                o.x = acc2[m][0] + bb.x;
                o.y = acc2[m][1] + bb.y;
                o.z = acc2[m][2] + bb.z;
                o.w = acc2[m][3] + bb.w;
                *(float4*)&out[(size_t)n * DIM_OUT + cg * 4] = o;
            }
        }
    }
}

// ---------------- tail outputs 1..4 (passthrough as f32) ----------------
__global__ __launch_bounds__(256) void tail_kernel(
    const int* __restrict__ sn, const int* __restrict__ en,
    const float* __restrict__ dfs, const float* __restrict__ df,
    float* __restrict__ out)
{
    int i = blockIdx.x * 256 + threadIdx.x;
    const int E = N_EDGES, N = N_NODES;
    int total = 3 * E + N;
    if (i >= total) return;
    float v;
    if (i < E) v = (float)sn[i];
    else if (i < 2 * E) v = (float)en[i - E];
    else if (i < 3 * E) v = dfs[i - 2 * E];
    else v = df[i - 3 * E];
    out[(size_t)N * DIM_OUT + (size_t)i] = v;
}

extern "C" void kernel_launch(void* const* d_in, const int* in_sizes, int n_in,
                              void* d_out, int out_size, void* d_ws, size_t ws_size,
                              hipStream_t stream) {
    const float* y   = (const float*)d_in[0];
    const int* start = (const int*)d_in[1];
    const int* endn  = (const int*)d_in[2];
    const float* dfs = (const float*)d_in[3];
    const float* df  = (const float*)d_in[4];
    const float* W1  = (const float*)d_in[5];
    const float* b1  = (const float*)d_in[6];
    const float* W2  = (const float*)d_in[7];
    const float* b2  = (const float*)d_in[8];
    float* out = (float*)d_out;

    const int N = N_NODES, E = N_EDGES;
    const size_t Y_ELEMS = (size_t)N * DIM_IN;  // 4.8M floats

    // Workspace carve: same ~52 MB footprint R7/R8 proved fits.
    char* ws = (char*)d_ws;
    size_t off = 0;
    auto carve = [&](size_t bytes) -> void* {
        void* p = ws + off;
        off = (off + bytes + 255) & ~(size_t)255;
        return p;
    };
    int*   cnt    = (int*)carve((size_t)N * 4);        // reused as cursor
    int*   rowptr = (int*)carve((size_t)(N + 1) * 4);
    int*   bsum   = (int*)carve((size_t)SCAN_NB * 4);
    int2*  edges  = (int2*)carve((size_t)E * 8);       // packed (src, w)
    float* y1     = (float*)carve(Y_ELEMS * 4);
    float* y2     = (float*)carve(Y_ELEMS * 4);
    size_t CSR_NEED = off;                              // ~52 MB

    if (ws_size >= CSR_NEED) {
        // ---- CSR gather path ----
        zero_kernel<<<(N + 255) / 256, 256, 0, stream>>>(cnt, N);
        count_kernel<<<(E + 255) / 256, 256, 0, stream>>>(endn, cnt, E);
        block_sum_kernel<<<SCAN_NB, SCAN_BLK, 0, stream>>>(cnt, bsum, N);
        scan_bsum_kernel<<<1, 512, 0, stream>>>(bsum, SCAN_NB);
        scan_write_kernel<<<SCAN_NB, SCAN_BLK, 0, stream>>>(cnt, bsum, rowptr,
                                                            /*cursor=*/cnt, N, E);
        fill_kernel<<<(E + 255) / 256, 256, 0, stream>>>(start, endn, dfs,
                                                         /*cursor=*/cnt, edges, E);
        // Pass 1: y1 = gather-sum(y * w)
        prop_kernel<<<(N + 3) / 4, dim3(48, 4), 0, stream>>>(
            y, y1, rowptr, edges, df, 0, N);
        // Pass 2: y2 = gather-sum(y1 * w * df[src])
        prop_kernel<<<(N + 3) / 4, dim3(48, 4), 0, stream>>>(
            y1, y2, rowptr, edges, df, 1, N);
    } else {
        // ---- fallback: atomic-scatter path (needs 38.4 MB) ----
        float* fy1 = (float*)d_ws;
        float* fy2 = fy1 + Y_ELEMS;
        y2 = fy2;
        int zn = (int)(2 * Y_ELEMS);
        zerof_kernel<<<(zn + 255) / 256, 256, 0, stream>>>(fy1, zn);
        scatter1_kernel<<<(E + 3) / 4, dim3(48, 4), 0, stream>>>(y, fy1, start, endn,
                                                                 dfs, E);
        scatter2_kernel<<<(E + 3) / 4, dim3(48, 4), 0, stream>>>(fy1, fy2, start, endn,
                                                                 dfs, df, E);
    }

    // MLP on x = y2*df -> out[0 .. N*128)
    mlp_kernel<<<(N + 63) / 64, 256, 0, stream>>>(y2, df, W1, b1, W2, b2, out, N);

    // Outputs 1..4 passthrough
    {
        int total = 3 * E + N;
        tail_kernel<<<(total + 255) / 256, 256, 0, stream>>>(start, endn, dfs, df, out);
    }
}